// Round 9
// baseline (398.273 us; speedup 1.0000x reference)
//
#include <hip/hip_runtime.h>

#define HH 1024
#define WW 1024
#define NB 16
#define NTH 3
#define BAND 32
#define NBAND (HH/BAND)       // 32
#define NSTRIP 11             // strips of 128 cols, 96-col yield: 11*96 = 1056 >= 1024
#define ACC_BYTES 4096

typedef __fp16 h2 __attribute__((ext_vector_type(2)));

// sigmoid(10*(v-th)) for th = 0, 0.5, 1.0 sharing one exp
__device__ __forceinline__ void sig3(float v, float* sf){
  const float e = __expf(-10.0f * v);
  sf[0] = __fdividef(1.0f, 1.0f + e);
  sf[1] = __fdividef(1.0f, 1.0f + e*148.41315910257660f);
  sf[2] = __fdividef(1.0f, 1.0f + e*22026.465794806718f);
}

__device__ __forceinline__ h2 bph(int idx4, h2 v){
  int s; __builtin_memcpy(&s, &v, 4);
  const int r = __builtin_amdgcn_ds_bpermute(idx4, s);
  h2 out; __builtin_memcpy(&out, &r, 4); return out;
}

__global__ __launch_bounds__(256) void fss_fused(
    const float* __restrict__ F_, const float* __restrict__ O_,
    double* __restrict__ accum)
{
  const int tid = threadIdx.x;
  const int ln  = tid & 63;
  const int w   = (blockIdx.x << 2) + (tid >> 6);   // global wave id
  const int s   = w % NSTRIP;
  const int rem = w / NSTRIP;
  const int band = rem & (NBAND-1);
  const int img  = rem / NBAND;
  const int y0 = band * BAND;
  const int x0 = 96*s - 16 + 2*ln;                  // owned col pair (x0, x0+1)
  const bool colok = ((unsigned)x0 < WW);
  const bool act   = (ln >= 8) && (ln < 56) && colok;

  const float* F = F_ + (size_t)img*HH*WW;
  const float* O = O_ + (size_t)img*HH*WW;

  // vertical window state (f32)
  float c9f[NTH][2]={{0}}, c9o[NTH][2]={{0}}, c33f[NTH][2]={{0}}, c33o[NTH][2]={{0}};
  float s1d[NTH]={0}, s1r[NTH]={0}, s9d[NTH]={0}, s9r[NTH]={0},
        s33d[NTH]={0}, s33r[NTH]={0};

  // precomputed ds_bpermute byte indices (lane index << 2, wrap &63)
  const int i_m1 = ((ln-1)&63)<<2, i_m2 = ((ln-2)&63)<<2;
  const int i_m4 = ((ln-4)&63)<<2, i_m8 = ((ln-8)&63)<<2;
  const int i_p1 = ((ln+1)&63)<<2, i_p2 = ((ln+2)&63)<<2;
  const int i_p7 = ((ln+7)&63)<<2, i_p8 = ((ln+8)&63)<<2;

  // ---- warmup: rows [y0-16, y0+16] ----
  #pragma unroll 1
  for (int r = y0-16; r <= y0+16; ++r){
    if ((unsigned)r >= HH) continue;
    float2 fv = {0,0}, ov = {0,0};
    if (colok){
      fv = *(const float2*)&F[(size_t)r*WW + x0];
      ov = *(const float2*)&O[(size_t)r*WW + x0];
    }
    const bool in9  = (r >= y0-4) && (r <= y0+4);
    const bool ink1 = (r >= y0)   && (r <= y0+4);
    float sf0[3], sf1[3]; sig3(fv.x, sf0); sig3(fv.y, sf1);
    #pragma unroll
    for (int t = 0; t < NTH; ++t){
      const float th = 0.5f*(float)t;
      const float so0 = (ov.x > th) ? 1.f : 0.f, so1 = (ov.y > th) ? 1.f : 0.f;
      c33f[t][0] += sf0[t]; c33f[t][1] += sf1[t];
      c33o[t][0] += so0;    c33o[t][1] += so1;
      if (in9){ c9f[t][0] += sf0[t]; c9f[t][1] += sf1[t];
                c9o[t][0] += so0;    c9o[t][1] += so1; }
      if (ink1){
        const float d0 = sf0[t]-so0, d1 = sf1[t]-so1;
        s1d[t] += d0*d0 + d1*d1;
        s1r[t] += sf0[t]*sf0[t] + so0 + sf1[t]*sf1[t] + so1;   // so^2 == so
      }
    }
  }

  // ---- main loop: no barriers, no LDS (bpermute only), f16-packed horizontal ----
  #pragma unroll 1
  for (int y = y0; y < y0 + BAND; ++y){
    // issue boundary-row loads first (latency overlaps the shuffle phase)
    const int ri9 = y+5, ro9 = y-4, ri33 = y+17, ro33 = y-16;
    const bool bi9 = (ri9 < HH), bo9 = (ro9 >= 0), bi33 = (ri33 < HH), bo33 = (ro33 >= 0);
    float2 vi9f={0,0}, vi9o={0,0}, vo9f={0,0}, vo9o={0,0};
    float2 vi33f={0,0}, vi33o={0,0}, vo33f={0,0}, vo33o={0,0};
    if (colok){
      if (bi9 ){ vi9f  = *(const float2*)&F[(size_t)ri9 *WW + x0]; vi9o  = *(const float2*)&O[(size_t)ri9 *WW + x0]; }
      if (bo9 ){ vo9f  = *(const float2*)&F[(size_t)ro9 *WW + x0]; vo9o  = *(const float2*)&O[(size_t)ro9 *WW + x0]; }
      if (bi33){ vi33f = *(const float2*)&F[(size_t)ri33*WW + x0]; vi33o = *(const float2*)&O[(size_t)ri33*WW + x0]; }
      if (bo33){ vo33f = *(const float2*)&F[(size_t)ro33*WW + x0]; vo33o = *(const float2*)&O[(size_t)ro33*WW + x0]; }
    }

    // horizontal windows + stats for row y (state centered at y), (f,o) packed f16
    #pragma unroll
    for (int t = 0; t < NTH; ++t){
      // ---- 33-window via packed unmasked window tree over column-pair sums ----
      // w16[l] = sum of pair-sums l-15..l; wrap garbage confined to halo lanes.
      h2 wv16 = __builtin_amdgcn_cvt_pkrtz(c33f[t][0] + c33f[t][1],
                                           c33o[t][0] + c33o[t][1]);
      wv16 = wv16 + bph(i_m1, wv16);
      wv16 = wv16 + bph(i_m2, wv16);
      wv16 = wv16 + bph(i_m4, wv16);
      wv16 = wv16 + bph(i_m8, wv16);
      const h2 c0 = __builtin_amdgcn_cvt_pkrtz(c33f[t][0], c33o[t][0]);
      const h2 c1 = __builtin_amdgcn_cvt_pkrtz(c33f[t][1], c33o[t][1]);
      const h2 h33_0 = bph(i_p7, wv16) + bph(i_p8, c0);
      const h2 h33_1 = bph(i_p8, wv16) + bph(i_m8, c1);

      // ---- 9-window via packed direct lane taps ----
      const h2 q  = __builtin_amdgcn_cvt_pkrtz(c9f[t][0] + c9f[t][1],
                                               c9o[t][0] + c9o[t][1]);
      const h2 q0 = __builtin_amdgcn_cvt_pkrtz(c9f[t][0], c9o[t][0]);
      const h2 q1 = __builtin_amdgcn_cvt_pkrtz(c9f[t][1], c9o[t][1]);
      const h2 mid = q + bph(i_m1, q) + bph(i_p1, q);
      const h2 h9_0 = mid + bph(i_m2, q) + bph(i_p2, q0);
      const h2 h9_1 = mid + bph(i_p2, q) + bph(i_m2, q1);

      const float F90 = (float)h9_0[0]*(1.f/81.f), O90 = (float)h9_0[1]*(1.f/81.f);
      const float F91 = (float)h9_1[0]*(1.f/81.f), O91 = (float)h9_1[1]*(1.f/81.f);
      const float d90 = F90-O90, d91 = F91-O91;
      s9d[t] += d90*d90 + d91*d91;
      s9r[t] += F90*F90 + O90*O90 + F91*F91 + O91*O91;
      const float Fa0 = (float)h33_0[0]*(1.f/1089.f), Oa0 = (float)h33_0[1]*(1.f/1089.f);
      const float Fa1 = (float)h33_1[0]*(1.f/1089.f), Oa1 = (float)h33_1[1]*(1.f/1089.f);
      const float da0 = Fa0-Oa0, da1 = Fa1-Oa1;
      s33d[t] += da0*da0 + da1*da1;
      s33r[t] += Fa0*Fa0 + Oa0*Oa0 + Fa1*Fa1 + Oa1*Oa1;
    }

    // slide vertical windows to center y+1 (+ k=1 stats on entering 9-row)
    if (bi9){
      float sf0[3], sf1[3]; sig3(vi9f.x, sf0); sig3(vi9f.y, sf1);
      const bool k1on = (ri9 < y0 + BAND);
      #pragma unroll
      for (int t = 0; t < NTH; ++t){
        const float th = 0.5f*(float)t;
        const float so0 = (vi9o.x > th) ? 1.f : 0.f, so1 = (vi9o.y > th) ? 1.f : 0.f;
        c9f[t][0] += sf0[t]; c9f[t][1] += sf1[t];
        c9o[t][0] += so0;    c9o[t][1] += so1;
        if (k1on){
          const float d0 = sf0[t]-so0, d1 = sf1[t]-so1;
          s1d[t] += d0*d0 + d1*d1;
          s1r[t] += sf0[t]*sf0[t] + so0 + sf1[t]*sf1[t] + so1;
        }
      }
    }
    if (bo9){
      float sf0[3], sf1[3]; sig3(vo9f.x, sf0); sig3(vo9f.y, sf1);
      #pragma unroll
      for (int t = 0; t < NTH; ++t){
        const float th = 0.5f*(float)t;
        const float so0 = (vo9o.x > th) ? 1.f : 0.f, so1 = (vo9o.y > th) ? 1.f : 0.f;
        c9f[t][0] -= sf0[t]; c9f[t][1] -= sf1[t];
        c9o[t][0] -= so0;    c9o[t][1] -= so1;
      }
    }
    if (bi33){
      float sf0[3], sf1[3]; sig3(vi33f.x, sf0); sig3(vi33f.y, sf1);
      #pragma unroll
      for (int t = 0; t < NTH; ++t){
        const float th = 0.5f*(float)t;
        const float so0 = (vi33o.x > th) ? 1.f : 0.f, so1 = (vi33o.y > th) ? 1.f : 0.f;
        c33f[t][0] += sf0[t]; c33f[t][1] += sf1[t];
        c33o[t][0] += so0;    c33o[t][1] += so1;
      }
    }
    if (bo33){
      float sf0[3], sf1[3]; sig3(vo33f.x, sf0); sig3(vo33f.y, sf1);
      #pragma unroll
      for (int t = 0; t < NTH; ++t){
        const float th = 0.5f*(float)t;
        const float so0 = (vo33o.x > th) ? 1.f : 0.f, so1 = (vo33o.y > th) ? 1.f : 0.f;
        c33f[t][0] -= sf0[t]; c33f[t][1] -= sf1[t];
        c33o[t][0] -= so0;    c33o[t][1] -= so1;
      }
    }
  }

  // ---- mask halo lanes, wave-reduce, per-wave f64 atomics ----
  if (!act){
    #pragma unroll
    for (int t = 0; t < NTH; ++t){
      s1d[t]=0; s1r[t]=0; s9d[t]=0; s9r[t]=0; s33d[t]=0; s33r[t]=0;
    }
  }
  #define WRED(v) { _Pragma("unroll") \
    for (int d = 32; d; d >>= 1) v += __shfl_down(v, (unsigned)d, 64); }
  #pragma unroll
  for (int t = 0; t < NTH; ++t){
    WRED(s1d[t]);  WRED(s1r[t]);
    WRED(s9d[t]);  WRED(s9r[t]);
    WRED(s33d[t]); WRED(s33r[t]);
  }
  if (ln == 0){
    #pragma unroll
    for (int t = 0; t < NTH; ++t){
      double* a = accum + (size_t)(img*NTH + t)*6;
      atomicAdd(&a[0], (double)s1d[t]);
      atomicAdd(&a[1], (double)s1r[t]);
      atomicAdd(&a[2], (double)s9d[t]);
      atomicAdd(&a[3], (double)s9r[t]);
      atomicAdd(&a[4], (double)s33d[t]);
      atomicAdd(&a[5], (double)s33r[t]);
    }
  }
}

__global__ void fss_final(const double* __restrict__ accum, float* __restrict__ out)
{
  if (threadIdx.x == 0 && blockIdx.x == 0){
    const double HW = (double)HH * (double)WW;
    double total = 0.0;
    for (int t = 0; t < NTH; ++t){
      for (int k = 0; k < 3; ++k){
        double s = 0.0;
        for (int img = 0; img < NB; ++img){
          const double* a = accum + (size_t)(img*NTH + t)*6 + (size_t)k*2;
          const double mse  = a[0] / HW;
          const double mref = a[1] / HW;
          s += 1.0 - mse / (mref + 1e-8);
        }
        total += s / (double)NB;
      }
    }
    out[0] = (float)(1.0 - total/9.0);
  }
}

extern "C" void kernel_launch(void* const* d_in, const int* in_sizes, int n_in,
                              void* d_out, int out_size, void* d_ws, size_t ws_size,
                              hipStream_t stream)
{
  const float* fcst = (const float*)d_in[0];
  const float* obs  = (const float*)d_in[1];
  float* out = (float*)d_out;
  double* accum = (double*)d_ws;

  const int nwaves = NSTRIP * NBAND * NB;   // 5632
  const int nblocks = nwaves / 4;           // 1408

  hipMemsetAsync(d_ws, 0, ACC_BYTES, stream);
  hipLaunchKernelGGL(fss_fused, dim3(nblocks), dim3(256), 0, stream,
                     fcst, obs, accum);
  hipLaunchKernelGGL(fss_final, dim3(1), dim3(64), 0, stream, accum, out);
}

// Round 10
// 346.518 us; speedup vs baseline: 1.1494x; 1.1494x over previous
//
#include <hip/hip_runtime.h>

#define HH 1024
#define WW 1024
#define NB 16
#define NTH 3
#define BAND 64
#define NBAND (HH/BAND)       // 16
#define NSTRIP 11             // strips of 128 cols, 96-col yield: 11*96 = 1056 >= 1024
#define ACC_BYTES 4096

typedef __fp16 h2 __attribute__((ext_vector_type(2)));

struct State {
  float c9f[NTH][2], c9o[NTH][2], c33f[NTH][2], c33o[NTH][2];
};

// sigmoid(10*(v-th)) for th = 0, 0.5, 1.0 sharing one exp
__device__ __forceinline__ void sig3(float v, float* sf){
  const float e = __expf(-10.0f * v);
  sf[0] = __fdividef(1.0f, 1.0f + e);
  sf[1] = __fdividef(1.0f, 1.0f + e*148.41315910257660f);
  sf[2] = __fdividef(1.0f, 1.0f + e*22026.465794806718f);
}

__device__ __forceinline__ h2 bph(int idx4, h2 v){
  int s; __builtin_memcpy(&s, &v, 4);
  const int r = __builtin_amdgcn_ds_bpermute(idx4, s);
  h2 out; __builtin_memcpy(&out, &r, 4); return out;
}

__global__ __launch_bounds__(256) void fss_fused(
    const float* __restrict__ F_, const float* __restrict__ O_,
    double* __restrict__ accum)
{
  const int tid = threadIdx.x;
  const int ln  = tid & 63;
  const int w   = (blockIdx.x << 2) + (tid >> 6);   // global wave id
  const int s   = w % NSTRIP;
  const int rem = w / NSTRIP;
  const int band = rem & (NBAND-1);
  const int img  = rem / NBAND;
  const int y0 = band * BAND;
  const int x0 = 96*s - 16 + 2*ln;                  // owned col pair (x0, x0+1)
  const bool colok = ((unsigned)x0 < WW);
  const bool act   = (ln >= 8) && (ln < 56) && colok;

  const float* F = F_ + (size_t)img*HH*WW;
  const float* O = O_ + (size_t)img*HH*WW;

  State S{};    // zero-initialized vertical window state (f32)
  float s1d[NTH]={0}, s1r[NTH]={0}, s9d[NTH]={0}, s9r[NTH]={0},
        s33d[NTH]={0}, s33r[NTH]={0};

  // precomputed ds_bpermute byte indices (lane index << 2, wrap &63)
  const int i_m1 = ((ln-1)&63)<<2, i_m2 = ((ln-2)&63)<<2;
  const int i_m4 = ((ln-4)&63)<<2, i_m8 = ((ln-8)&63)<<2;
  const int i_p1 = ((ln+1)&63)<<2, i_p2 = ((ln+2)&63)<<2;
  const int i_p7 = ((ln+7)&63)<<2, i_p8 = ((ln+8)&63)<<2;

  // ---- warmup: rows [y0-16, y0+16] ----
  #pragma unroll 1
  for (int r = y0-16; r <= y0+16; ++r){
    if ((unsigned)r >= HH) continue;
    float2 fv = {0,0}, ov = {0,0};
    if (colok){
      fv = *(const float2*)&F[(size_t)r*WW + x0];
      ov = *(const float2*)&O[(size_t)r*WW + x0];
    }
    const bool in9  = (r >= y0-4) && (r <= y0+4);
    const bool ink1 = (r >= y0)   && (r <= y0+4);
    float sf0[3], sf1[3]; sig3(fv.x, sf0); sig3(fv.y, sf1);
    #pragma unroll
    for (int t = 0; t < NTH; ++t){
      const float th = 0.5f*(float)t;
      const float so0 = (ov.x > th) ? 1.f : 0.f, so1 = (ov.y > th) ? 1.f : 0.f;
      S.c33f[t][0] += sf0[t]; S.c33f[t][1] += sf1[t];
      S.c33o[t][0] += so0;    S.c33o[t][1] += so1;
      if (in9){ S.c9f[t][0] += sf0[t]; S.c9f[t][1] += sf1[t];
                S.c9o[t][0] += so0;    S.c9o[t][1] += so1; }
      if (ink1){
        const float d0 = sf0[t]-so0, d1 = sf1[t]-so1;
        s1d[t] += d0*d0 + d1*d1;
        s1r[t] += sf0[t]*sf0[t] + so0 + sf1[t]*sf1[t] + so1;   // so^2 == so
      }
    }
  }

  // slide src(centered y) -> dst(centered y+1), accumulating k=1 stats on entering 9-row
  auto slide_into = [&](State& dst, const State& src,
                        float2 fi9, float2 oi9, float2 fo9, float2 oo9,
                        float2 fi33, float2 oi33, float2 fo33, float2 oo33,
                        bool bi9, bool bo9, bool bi33, bool bo33, bool k1on){
    #pragma unroll
    for (int t = 0; t < NTH; ++t){
      #pragma unroll
      for (int c = 0; c < 2; ++c){
        dst.c9f[t][c]  = src.c9f[t][c];  dst.c9o[t][c]  = src.c9o[t][c];
        dst.c33f[t][c] = src.c33f[t][c]; dst.c33o[t][c] = src.c33o[t][c];
      }
    }
    if (bi9){
      float sf0[3], sf1[3]; sig3(fi9.x, sf0); sig3(fi9.y, sf1);
      #pragma unroll
      for (int t = 0; t < NTH; ++t){
        const float th = 0.5f*(float)t;
        const float so0 = (oi9.x > th) ? 1.f : 0.f, so1 = (oi9.y > th) ? 1.f : 0.f;
        dst.c9f[t][0] += sf0[t]; dst.c9f[t][1] += sf1[t];
        dst.c9o[t][0] += so0;    dst.c9o[t][1] += so1;
        if (k1on){
          const float d0 = sf0[t]-so0, d1 = sf1[t]-so1;
          s1d[t] += d0*d0 + d1*d1;
          s1r[t] += sf0[t]*sf0[t] + so0 + sf1[t]*sf1[t] + so1;
        }
      }
    }
    if (bo9){
      float sf0[3], sf1[3]; sig3(fo9.x, sf0); sig3(fo9.y, sf1);
      #pragma unroll
      for (int t = 0; t < NTH; ++t){
        const float th = 0.5f*(float)t;
        const float so0 = (oo9.x > th) ? 1.f : 0.f, so1 = (oo9.y > th) ? 1.f : 0.f;
        dst.c9f[t][0] -= sf0[t]; dst.c9f[t][1] -= sf1[t];
        dst.c9o[t][0] -= so0;    dst.c9o[t][1] -= so1;
      }
    }
    if (bi33){
      float sf0[3], sf1[3]; sig3(fi33.x, sf0); sig3(fi33.y, sf1);
      #pragma unroll
      for (int t = 0; t < NTH; ++t){
        const float th = 0.5f*(float)t;
        const float so0 = (oi33.x > th) ? 1.f : 0.f, so1 = (oi33.y > th) ? 1.f : 0.f;
        dst.c33f[t][0] += sf0[t]; dst.c33f[t][1] += sf1[t];
        dst.c33o[t][0] += so0;    dst.c33o[t][1] += so1;
      }
    }
    if (bo33){
      float sf0[3], sf1[3]; sig3(fo33.x, sf0); sig3(fo33.y, sf1);
      #pragma unroll
      for (int t = 0; t < NTH; ++t){
        const float th = 0.5f*(float)t;
        const float so0 = (oo33.x > th) ? 1.f : 0.f, so1 = (oo33.y > th) ? 1.f : 0.f;
        dst.c33f[t][0] -= sf0[t]; dst.c33f[t][1] -= sf1[t];
        dst.c33o[t][0] -= so0;    dst.c33o[t][1] -= so1;
      }
    }
  };

  // horizontal windows + stats for the row the given state is centered on
  auto hstats = [&](const State& Sx){
    #pragma unroll
    for (int t = 0; t < NTH; ++t){
      // 33-window via packed unmasked window tree over column-pair sums
      h2 wv16 = __builtin_amdgcn_cvt_pkrtz(Sx.c33f[t][0] + Sx.c33f[t][1],
                                           Sx.c33o[t][0] + Sx.c33o[t][1]);
      wv16 = wv16 + bph(i_m1, wv16);
      wv16 = wv16 + bph(i_m2, wv16);
      wv16 = wv16 + bph(i_m4, wv16);
      wv16 = wv16 + bph(i_m8, wv16);
      const h2 c0 = __builtin_amdgcn_cvt_pkrtz(Sx.c33f[t][0], Sx.c33o[t][0]);
      const h2 c1 = __builtin_amdgcn_cvt_pkrtz(Sx.c33f[t][1], Sx.c33o[t][1]);
      const h2 h33_0 = bph(i_p7, wv16) + bph(i_p8, c0);
      const h2 h33_1 = bph(i_p8, wv16) + bph(i_m8, c1);

      // 9-window via packed direct lane taps
      const h2 q  = __builtin_amdgcn_cvt_pkrtz(Sx.c9f[t][0] + Sx.c9f[t][1],
                                               Sx.c9o[t][0] + Sx.c9o[t][1]);
      const h2 q0 = __builtin_amdgcn_cvt_pkrtz(Sx.c9f[t][0], Sx.c9o[t][0]);
      const h2 q1 = __builtin_amdgcn_cvt_pkrtz(Sx.c9f[t][1], Sx.c9o[t][1]);
      const h2 mid = q + bph(i_m1, q) + bph(i_p1, q);
      const h2 h9_0 = mid + bph(i_m2, q) + bph(i_p2, q0);
      const h2 h9_1 = mid + bph(i_p2, q) + bph(i_m2, q1);

      const float F90 = (float)h9_0[0]*(1.f/81.f), O90 = (float)h9_0[1]*(1.f/81.f);
      const float F91 = (float)h9_1[0]*(1.f/81.f), O91 = (float)h9_1[1]*(1.f/81.f);
      const float d90 = F90-O90, d91 = F91-O91;
      s9d[t] += d90*d90 + d91*d91;
      s9r[t] += F90*F90 + O90*O90 + F91*F91 + O91*O91;
      const float Fa0 = (float)h33_0[0]*(1.f/1089.f), Oa0 = (float)h33_0[1]*(1.f/1089.f);
      const float Fa1 = (float)h33_1[0]*(1.f/1089.f), Oa1 = (float)h33_1[1]*(1.f/1089.f);
      const float da0 = Fa0-Oa0, da1 = Fa1-Oa1;
      s33d[t] += da0*da0 + da1*da1;
      s33r[t] += Fa0*Fa0 + Oa0*Oa0 + Fa1*Fa1 + Oa1*Oa1;
    }
  };

  #define LD2(P, r) (*(const float2*)&(P)[(size_t)(r)*WW + x0])

  // ---- main loop: unroll-2, no barriers, no LDS; two independent shuffle
  //      chains (rows y and y+1) interleave to hide bpermute latency ----
  #pragma unroll 1
  for (int y = y0; y < y0 + BAND; y += 2){
    const int rAi9=y+5, rAo9=y-4, rAi33=y+17, rAo33=y-16;
    const int rBi9=y+6, rBo9=y-3, rBi33=y+18, rBo33=y-15;
    const bool bAi9=rAi9<HH, bAo9=rAo9>=0, bAi33=rAi33<HH, bAo33=rAo33>=0;
    const bool bBi9=rBi9<HH, bBo9=rBo9>=0, bBi33=rBi33<HH, bBo33=rBo33>=0;
    float2 Afi9={0,0},Aoi9={0,0},Afo9={0,0},Aoo9={0,0};
    float2 Afi33={0,0},Aoi33={0,0},Afo33={0,0},Aoo33={0,0};
    float2 Bfi9={0,0},Boi9={0,0},Bfo9={0,0},Boo9={0,0};
    float2 Bfi33={0,0},Boi33={0,0},Bfo33={0,0},Boo33={0,0};
    if (colok){
      if (bAi9 ){ Afi9  = LD2(F,rAi9);  Aoi9  = LD2(O,rAi9);  }
      if (bAo9 ){ Afo9  = LD2(F,rAo9);  Aoo9  = LD2(O,rAo9);  }
      if (bAi33){ Afi33 = LD2(F,rAi33); Aoi33 = LD2(O,rAi33); }
      if (bAo33){ Afo33 = LD2(F,rAo33); Aoo33 = LD2(O,rAo33); }
      if (bBi9 ){ Bfi9  = LD2(F,rBi9);  Boi9  = LD2(O,rBi9);  }
      if (bBo9 ){ Bfo9  = LD2(F,rBo9);  Boo9  = LD2(O,rBo9);  }
      if (bBi33){ Bfi33 = LD2(F,rBi33); Boi33 = LD2(O,rBi33); }
      if (bBo33){ Bfo33 = LD2(F,rBo33); Boo33 = LD2(O,rBo33); }
    }

    State S1;
    slide_into(S1, S, Afi9,Aoi9,Afo9,Aoo9,Afi33,Aoi33,Afo33,Aoo33,
               bAi9,bAo9,bAi33,bAo33, rAi9 < y0+BAND);
    hstats(S);    // row y
    hstats(S1);   // row y+1 (independent chains, interleaved by scheduler)
    slide_into(S, S1, Bfi9,Boi9,Bfo9,Boo9,Bfi33,Boi33,Bfo33,Boo33,
               bBi9,bBo9,bBi33,bBo33, rBi9 < y0+BAND);
  }

  // ---- mask halo lanes, wave-reduce, per-wave f64 atomics ----
  if (!act){
    #pragma unroll
    for (int t = 0; t < NTH; ++t){
      s1d[t]=0; s1r[t]=0; s9d[t]=0; s9r[t]=0; s33d[t]=0; s33r[t]=0;
    }
  }
  #define WRED(v) { _Pragma("unroll") \
    for (int d = 32; d; d >>= 1) v += __shfl_down(v, (unsigned)d, 64); }
  #pragma unroll
  for (int t = 0; t < NTH; ++t){
    WRED(s1d[t]);  WRED(s1r[t]);
    WRED(s9d[t]);  WRED(s9r[t]);
    WRED(s33d[t]); WRED(s33r[t]);
  }
  if (ln == 0){
    #pragma unroll
    for (int t = 0; t < NTH; ++t){
      double* a = accum + (size_t)(img*NTH + t)*6;
      atomicAdd(&a[0], (double)s1d[t]);
      atomicAdd(&a[1], (double)s1r[t]);
      atomicAdd(&a[2], (double)s9d[t]);
      atomicAdd(&a[3], (double)s9r[t]);
      atomicAdd(&a[4], (double)s33d[t]);
      atomicAdd(&a[5], (double)s33r[t]);
    }
  }
}

__global__ void fss_final(const double* __restrict__ accum, float* __restrict__ out)
{
  if (threadIdx.x == 0 && blockIdx.x == 0){
    const double HW = (double)HH * (double)WW;
    double total = 0.0;
    for (int t = 0; t < NTH; ++t){
      for (int k = 0; k < 3; ++k){
        double s = 0.0;
        for (int img = 0; img < NB; ++img){
          const double* a = accum + (size_t)(img*NTH + t)*6 + (size_t)k*2;
          const double mse  = a[0] / HW;
          const double mref = a[1] / HW;
          s += 1.0 - mse / (mref + 1e-8);
        }
        total += s / (double)NB;
      }
    }
    out[0] = (float)(1.0 - total/9.0);
  }
}

extern "C" void kernel_launch(void* const* d_in, const int* in_sizes, int n_in,
                              void* d_out, int out_size, void* d_ws, size_t ws_size,
                              hipStream_t stream)
{
  const float* fcst = (const float*)d_in[0];
  const float* obs  = (const float*)d_in[1];
  float* out = (float*)d_out;
  double* accum = (double*)d_ws;

  const int nwaves = NSTRIP * NBAND * NB;   // 2816
  const int nblocks = nwaves / 4;           // 704

  hipMemsetAsync(d_ws, 0, ACC_BYTES, stream);
  hipLaunchKernelGGL(fss_fused, dim3(nblocks), dim3(256), 0, stream,
                     fcst, obs, accum);
  hipLaunchKernelGGL(fss_final, dim3(1), dim3(64), 0, stream, accum, out);
}

// Round 11
// 245.729 us; speedup vs baseline: 1.6208x; 1.4102x over previous
//
#include <hip/hip_runtime.h>

#define HH 1024
#define WW 1024
#define NB 16
#define NTH 3
#define BAND 64
#define NBAND (HH/BAND)       // 16
#define NSTRIP 11             // strips of 128 cols, 96-col yield: 11*96 = 1056 >= 1024
#define ACC_BYTES 4096
#define NEGBIG -1e30f

typedef unsigned int u32;
typedef _Float16 hv __attribute__((ext_vector_type(2)));

__device__ __forceinline__ hv pkh(float a, float b){
  auto t = __builtin_amdgcn_cvt_pkrtz(a, b);   // v_cvt_pkrtz_f16_f32
  hv r; __builtin_memcpy(&r, &t, 4); return r;
}
__device__ __forceinline__ hv bph(int idx4, hv v){
  int s; __builtin_memcpy(&s, &v, 4);
  const int r = __builtin_amdgcn_ds_bpermute(idx4, s);
  hv o; __builtin_memcpy(&o, &r, 4); return o;
}
__device__ __forceinline__ hv swph(hv v){      // swap halves (v_alignbit rotate 16)
  u32 u; __builtin_memcpy(&u, &v, 4);
  u = (u >> 16) | (u << 16);
  hv o; __builtin_memcpy(&o, &u, 4); return o;
}
// raw stats: sd += 2*(h.f - h.o)^2 ; sr += h.f^2 + h.o^2   (normalize in fss_final)
__device__ __forceinline__ void dstat(hv h, float& sd, float& sr){
  const hv d = h - swph(h);
  sd = __builtin_amdgcn_fdot2(d, d, sd, false);
  sr = __builtin_amdgcn_fdot2(h, h, sr, false);
}

#if __has_builtin(__builtin_amdgcn_rcpf)
#define RCP(x) __builtin_amdgcn_rcpf(x)
#else
#define RCP(x) (1.0f/(x))
#endif
#if __has_builtin(__builtin_amdgcn_exp2f)
#define EXP2(x) __builtin_amdgcn_exp2f(x)
#else
#define EXP2(x) exp2f(x)
#endif

// sigmoid(10*(v-th)) for th = 0, 0.5, 1.0: 1/(1 + e*K_th), e = 2^(-10*log2e*v)
// v = NEGBIG -> e = +inf -> all sig = 0 (and obs compares false): masked lanes stay 0.
__device__ __forceinline__ void sig3(float v, float* sf){
  const float e = EXP2(-14.426950408889634f * v);
  sf[0] = RCP(1.0f + e);
  sf[1] = RCP(__builtin_fmaf(e, 148.41315910257660f, 1.0f));
  sf[2] = RCP(__builtin_fmaf(e, 22026.465794806718f, 1.0f));
}

__global__ __launch_bounds__(256) void fss_fused(
    const float* __restrict__ F_, const float* __restrict__ O_,
    double* __restrict__ accum)
{
  const int tid = threadIdx.x;
  const int ln  = tid & 63;
  const int w   = (blockIdx.x << 2) + (tid >> 6);   // global wave id
  const int s   = w % NSTRIP;
  const int rem = w / NSTRIP;
  const int band = rem & (NBAND-1);
  const int img  = rem / NBAND;
  const int y0 = band * BAND;
  const int x0 = 96*s - 16 + 2*ln;                  // owned col pair (x0, x0+1)
  const bool colok = ((unsigned)x0 < WW);
  const bool act   = (ln >= 8) && (ln < 56) && colok;

  const float* F = F_ + (size_t)img*HH*WW;
  const float* O = O_ + (size_t)img*HH*WW;

  // vertical window state (f32)
  float c9f[NTH][2]={{0}}, c9o[NTH][2]={{0}}, c33f[NTH][2]={{0}}, c33o[NTH][2]={{0}};
  float s1d[NTH]={0}, s1r[NTH]={0}, s9d[NTH]={0}, s9r[NTH]={0},
        s33d[NTH]={0}, s33r[NTH]={0};

  // precomputed ds_bpermute byte indices
  const int i_m1=((ln-1)&63)<<2, i_m2=((ln-2)&63)<<2, i_m4=((ln-4)&63)<<2, i_m8=((ln-8)&63)<<2;
  const int i_p1=((ln+1)&63)<<2, i_p2=((ln+2)&63)<<2, i_p7=((ln+7)&63)<<2, i_p8=((ln+8)&63)<<2;

  // ---- warmup: rows [y0-16, y0+16] ----
  #pragma unroll 1
  for (int r = y0-16; r <= y0+16; ++r){
    if ((unsigned)r >= HH) continue;
    float2 fv = {NEGBIG,NEGBIG}, ov = {NEGBIG,NEGBIG};
    if (colok){
      fv = *(const float2*)&F[(size_t)r*WW + x0];
      ov = *(const float2*)&O[(size_t)r*WW + x0];
    }
    const bool in9  = (r >= y0-4) && (r <= y0+4);
    const bool ink1 = (r >= y0)   && (r <= y0+4);
    float sf0[3], sf1[3]; sig3(fv.x, sf0); sig3(fv.y, sf1);
    #pragma unroll
    for (int t = 0; t < NTH; ++t){
      const float th = 0.5f*(float)t;
      const float so0 = (ov.x > th) ? 1.f : 0.f, so1 = (ov.y > th) ? 1.f : 0.f;
      c33f[t][0] += sf0[t]; c33f[t][1] += sf1[t];
      c33o[t][0] += so0;    c33o[t][1] += so1;
      if (in9){ c9f[t][0] += sf0[t]; c9f[t][1] += sf1[t];
                c9o[t][0] += so0;    c9o[t][1] += so1; }
      if (ink1){
        const float d0 = sf0[t]-so0, d1 = sf1[t]-so1;
        s1d[t] += d0*d0 + d1*d1;
        s1r[t] += sf0[t]*sf0[t] + so0 + sf1[t]*sf1[t] + so1;   // so^2 == so
      }
    }
  }

  // ---- main loop: no barriers, no LDS; in-place slide; dot2 raw stats ----
  #pragma unroll 1
  for (int y = y0; y < y0 + BAND; ++y){
    const int ri9 = y+5, ro9 = y-4, ri33 = y+17, ro33 = y-16;
    const bool bi9 = (ri9 < HH), bo9 = (ro9 >= 0), bi33 = (ri33 < HH), bo33 = (ro33 >= 0);
    float2 vi9f={NEGBIG,NEGBIG}, vi9o={NEGBIG,NEGBIG};
    float2 vo9f={NEGBIG,NEGBIG}, vo9o={NEGBIG,NEGBIG};
    float2 vi33f={NEGBIG,NEGBIG}, vi33o={NEGBIG,NEGBIG};
    float2 vo33f={NEGBIG,NEGBIG}, vo33o={NEGBIG,NEGBIG};
    if (colok){
      if (bi9 ){ vi9f  = *(const float2*)&F[(size_t)ri9 *WW + x0]; vi9o  = *(const float2*)&O[(size_t)ri9 *WW + x0]; }
      if (bo9 ){ vo9f  = *(const float2*)&F[(size_t)ro9 *WW + x0]; vo9o  = *(const float2*)&O[(size_t)ro9 *WW + x0]; }
      if (bi33){ vi33f = *(const float2*)&F[(size_t)ri33*WW + x0]; vi33o = *(const float2*)&O[(size_t)ri33*WW + x0]; }
      if (bo33){ vo33f = *(const float2*)&F[(size_t)ro33*WW + x0]; vo33o = *(const float2*)&O[(size_t)ro33*WW + x0]; }
    }

    // horizontal windows + raw stats for row y (state centered at y)
    #pragma unroll
    for (int t = 0; t < NTH; ++t){
      // 33-window: packed unmasked window tree over column-pair sums
      hv wv = pkh(c33f[t][0] + c33f[t][1], c33o[t][0] + c33o[t][1]);
      wv = wv + bph(i_m1, wv);
      wv = wv + bph(i_m2, wv);
      wv = wv + bph(i_m4, wv);
      wv = wv + bph(i_m8, wv);
      const hv c0 = pkh(c33f[t][0], c33o[t][0]);
      const hv c1 = pkh(c33f[t][1], c33o[t][1]);
      const hv h33_0 = bph(i_p7, wv) + bph(i_p8, c0);
      const hv h33_1 = bph(i_p8, wv) + bph(i_m8, c1);

      // 9-window: packed direct lane taps
      const hv q  = pkh(c9f[t][0] + c9f[t][1], c9o[t][0] + c9o[t][1]);
      const hv q0 = pkh(c9f[t][0], c9o[t][0]);
      const hv q1 = pkh(c9f[t][1], c9o[t][1]);
      const hv mid = q + bph(i_m1, q) + bph(i_p1, q);
      const hv h9_0 = mid + bph(i_m2, q) + bph(i_p2, q0);
      const hv h9_1 = mid + bph(i_p2, q) + bph(i_m2, q1);

      dstat(h9_0,  s9d[t],  s9r[t]);
      dstat(h9_1,  s9d[t],  s9r[t]);
      dstat(h33_0, s33d[t], s33r[t]);
      dstat(h33_1, s33d[t], s33r[t]);
    }

    // slide vertical windows to center y+1 (+ k=1 stats on entering 9-row)
    if (bi9){
      float sf0[3], sf1[3]; sig3(vi9f.x, sf0); sig3(vi9f.y, sf1);
      const bool k1on = (ri9 < y0 + BAND);
      #pragma unroll
      for (int t = 0; t < NTH; ++t){
        const float th = 0.5f*(float)t;
        const float so0 = (vi9o.x > th) ? 1.f : 0.f, so1 = (vi9o.y > th) ? 1.f : 0.f;
        c9f[t][0] += sf0[t]; c9f[t][1] += sf1[t];
        c9o[t][0] += so0;    c9o[t][1] += so1;
        if (k1on){
          const float d0 = sf0[t]-so0, d1 = sf1[t]-so1;
          s1d[t] += d0*d0 + d1*d1;
          s1r[t] += sf0[t]*sf0[t] + so0 + sf1[t]*sf1[t] + so1;
        }
      }
    }
    if (bo9){
      float sf0[3], sf1[3]; sig3(vo9f.x, sf0); sig3(vo9f.y, sf1);
      #pragma unroll
      for (int t = 0; t < NTH; ++t){
        const float th = 0.5f*(float)t;
        const float so0 = (vo9o.x > th) ? 1.f : 0.f, so1 = (vo9o.y > th) ? 1.f : 0.f;
        c9f[t][0] -= sf0[t]; c9f[t][1] -= sf1[t];
        c9o[t][0] -= so0;    c9o[t][1] -= so1;
      }
    }
    if (bi33){
      float sf0[3], sf1[3]; sig3(vi33f.x, sf0); sig3(vi33f.y, sf1);
      #pragma unroll
      for (int t = 0; t < NTH; ++t){
        const float th = 0.5f*(float)t;
        const float so0 = (vi33o.x > th) ? 1.f : 0.f, so1 = (vi33o.y > th) ? 1.f : 0.f;
        c33f[t][0] += sf0[t]; c33f[t][1] += sf1[t];
        c33o[t][0] += so0;    c33o[t][1] += so1;
      }
    }
    if (bo33){
      float sf0[3], sf1[3]; sig3(vo33f.x, sf0); sig3(vo33f.y, sf1);
      #pragma unroll
      for (int t = 0; t < NTH; ++t){
        const float th = 0.5f*(float)t;
        const float so0 = (vo33o.x > th) ? 1.f : 0.f, so1 = (vo33o.y > th) ? 1.f : 0.f;
        c33f[t][0] -= sf0[t]; c33f[t][1] -= sf1[t];
        c33o[t][0] -= so0;    c33o[t][1] -= so1;
      }
    }
  }

  // ---- mask halo lanes, wave-reduce, per-wave f64 atomics ----
  if (!act){
    #pragma unroll
    for (int t = 0; t < NTH; ++t){
      s1d[t]=0; s1r[t]=0; s9d[t]=0; s9r[t]=0; s33d[t]=0; s33r[t]=0;
    }
  }
  #define WRED(v) { _Pragma("unroll") \
    for (int d = 32; d; d >>= 1) v += __shfl_down(v, (unsigned)d, 64); }
  #pragma unroll
  for (int t = 0; t < NTH; ++t){
    WRED(s1d[t]);  WRED(s1r[t]);
    WRED(s9d[t]);  WRED(s9r[t]);
    WRED(s33d[t]); WRED(s33r[t]);
  }
  if (ln == 0){
    #pragma unroll
    for (int t = 0; t < NTH; ++t){
      double* a = accum + (size_t)(img*NTH + t)*6;
      atomicAdd(&a[0], (double)s1d[t]);
      atomicAdd(&a[1], (double)s1r[t]);
      atomicAdd(&a[2], (double)s9d[t]);
      atomicAdd(&a[3], (double)s9r[t]);
      atomicAdd(&a[4], (double)s33d[t]);
      atomicAdd(&a[5], (double)s33r[t]);
    }
  }
}

__global__ void fss_final(const double* __restrict__ accum, float* __restrict__ out)
{
  if (threadIdx.x == 0 && blockIdx.x == 0){
    const double HW = (double)HH * (double)WW;
    // raw k=9/33 stats: sd holds 2*(hf-ho)^2 sums, sr holds hf^2+ho^2 sums
    const double msc[3] = {1.0, 2.0*6561.0, 2.0*1185921.0};
    const double rsc[3] = {1.0, 6561.0, 1185921.0};
    double total = 0.0;
    for (int t = 0; t < NTH; ++t){
      for (int k = 0; k < 3; ++k){
        double sum = 0.0;
        for (int img = 0; img < NB; ++img){
          const double* a = accum + (size_t)(img*NTH + t)*6 + (size_t)k*2;
          const double mse  = a[0] / (msc[k]*HW);
          const double mref = a[1] / (rsc[k]*HW);
          sum += 1.0 - mse / (mref + 1e-8);
        }
        total += sum / (double)NB;
      }
    }
    out[0] = (float)(1.0 - total/9.0);
  }
}

extern "C" void kernel_launch(void* const* d_in, const int* in_sizes, int n_in,
                              void* d_out, int out_size, void* d_ws, size_t ws_size,
                              hipStream_t stream)
{
  const float* fcst = (const float*)d_in[0];
  const float* obs  = (const float*)d_in[1];
  float* out = (float*)d_out;
  double* accum = (double*)d_ws;

  const int nwaves = NSTRIP * NBAND * NB;   // 2816
  const int nblocks = nwaves / 4;           // 704

  hipMemsetAsync(d_ws, 0, ACC_BYTES, stream);
  hipLaunchKernelGGL(fss_fused, dim3(nblocks), dim3(256), 0, stream,
                     fcst, obs, accum);
  hipLaunchKernelGGL(fss_final, dim3(1), dim3(64), 0, stream, accum, out);
}